// Round 15
// baseline (148.477 us; speedup 1.0000x reference)
//
#include <hip/hip_runtime.h>

// Problem constants: B=4, L=2048, C=64, D=4
#define BB 4
#define LL 2048
#define CC 64
#define DD 4
#define AN (CC * DD)        // 256 A-entries per timestep per batch (c*4+i)
#define TPB 512             // threads per block
#define N4PB 4              // n4 values per block
#define NSEGS (TPB / N4PB)  // 128 time segments per chain
#define TT (LL / NSEGS)     // 16 timesteps per thread

typedef float f32x4 __attribute__((ext_vector_type(4)));

// ---------------------------------------------------------------------------
// FINAL: round-7 kernel verbatim — the measured best (dispatch ~50 us,
// dur 142.2 us). Session ledger (rounds 3-14) of structural alternatives,
// all measured worse: grid-sync fusion 914 us; block-per-chain time-lanes
// 80 us; TPB=1024 (allocator pins 64 VGPR, spills) 60 us; waves_per_eu /
// asm-pin (spill) 60-86 us; y_loc+RMW through HBM 81 us; N4PB=2 half-lines
// 66 us; half-chain lookback 77-86 us; LDS X-stash 55-60 us.
// Design rules this kernel satisfies:
//  (1) Quad lanes read full 64 B lines (16B/lane->1.4, 32B->1.65,
//      64B->2.2+ TB/s measured).
//  (2) Pass 2 re-reads X via compiler remat; re-reads are LLC-served
//      (FETCH 41 MB < 80 MB input). Fighting the allocator to hold X in
//      VGPRs across the scan always produced spills instead.
//  (3) One block per CU; chunked XCD swizzle keeps A-line sharers and
//      adjacent-n4 X/out lines on one XCD's L2.
// ---------------------------------------------------------------------------
__global__ __launch_bounds__(TPB) void pscan_onepass3(
    const float* __restrict__ A_re, const float* __restrict__ A_im,
    const f32x4* __restrict__ X_re4, const f32x4* __restrict__ X_im4,
    f32x4* __restrict__ out4) {
  // Chunked XCD swizzle, bijective on [0,256).
  const int sid = (blockIdx.x & 7) * 32 + (blockIdx.x >> 3);
  const int b    = sid >> 6;                 // [0,4)
  const int n4g  = sid & 63;                 // [0,64)
  const int tid  = threadIdx.x;
  const int n4l  = tid & (N4PB - 1);
  const int tseg = tid >> 2;                 // [0,128)
  const int n4   = n4g * N4PB + n4l;
  const int t0   = tseg * TT;
  const int base = (b * LL + t0) * AN + n4;  // index for A (float) and X (f32x4)

  // ---- pass 1: load A,X; compute segment aggregate ----
  float ar[TT], ai[TT];
  f32x4 xr[TT], xi[TT];
  float p_re = 1.f, p_im = 0.f;
  float s_re[4] = {0.f, 0.f, 0.f, 0.f};
  float s_im[4] = {0.f, 0.f, 0.f, 0.f};
#pragma unroll
  for (int t = 0; t < TT; ++t) {
    const float are = A_re[base + t * AN];
    const float aim = A_im[base + t * AN];
    ar[t] = are; ai[t] = aim;
    xr[t] = X_re4[base + t * AN];
    xi[t] = X_im4[base + t * AN];
    const float npre = are * p_re - aim * p_im;
    const float npim = are * p_im + aim * p_re;
    p_re = npre; p_im = npim;
#pragma unroll
    for (int j = 0; j < 4; ++j) {
      const float nsre = are * s_re[j] - aim * s_im[j] + xr[t][j];
      const float nsim = are * s_im[j] + aim * s_re[j] + xi[t][j];
      s_re[j] = nsre; s_im[j] = nsim;
    }
  }

  // ---- block-level inclusive Hillis-Steele scan (per n4l chain) ----
  // tuple q = tid, 11-float stride (11 coprime 32): worst aliasing 2-way
  // (lane i vs i+32) = free on CDNA4.
  __shared__ float lds[TPB * 11];
  const int q = tid * 11;
  lds[q + 0] = p_re; lds[q + 1] = p_im;
#pragma unroll
  for (int j = 0; j < 4; ++j) { lds[q + 2 + j] = s_re[j]; lds[q + 6 + j] = s_im[j]; }

  float vp_re = p_re, vp_im = p_im;
  float vs_re[4], vs_im[4];
#pragma unroll
  for (int j = 0; j < 4; ++j) { vs_re[j] = s_re[j]; vs_im[j] = s_im[j]; }

  for (int d = 1; d < NSEGS; d <<= 1) {      // 7 rounds
    __syncthreads();
    float wp_re = 1.f, wp_im = 0.f;
    float ws_re[4] = {0.f, 0.f, 0.f, 0.f};
    float ws_im[4] = {0.f, 0.f, 0.f, 0.f};
    if (tseg >= d) {
      const int q2 = q - d * (N4PB * 11);    // (tseg-d, same n4l)
      wp_re = lds[q2 + 0]; wp_im = lds[q2 + 1];
#pragma unroll
      for (int j = 0; j < 4; ++j) { ws_re[j] = lds[q2 + 2 + j]; ws_im[j] = lds[q2 + 6 + j]; }
    }
    __syncthreads();
    if (tseg >= d) {
      // combine(earlier = w, later = v): p' = vp*wp ; s' = vp*ws + vs
      const float np_re = vp_re * wp_re - vp_im * wp_im;
      const float np_im = vp_re * wp_im + vp_im * wp_re;
#pragma unroll
      for (int j = 0; j < 4; ++j) {
        const float ns_re = vp_re * ws_re[j] - vp_im * ws_im[j] + vs_re[j];
        const float ns_im = vp_re * ws_im[j] + vp_im * ws_re[j] + vs_im[j];
        vs_re[j] = ns_re; vs_im[j] = ns_im;
      }
      vp_re = np_re; vp_im = np_im;
      lds[q + 0] = vp_re; lds[q + 1] = vp_im;
#pragma unroll
      for (int j = 0; j < 4; ++j) { lds[q + 2 + j] = vs_re[j]; lds[q + 6 + j] = vs_im[j]; }
    }
  }
  __syncthreads();

  // ---- exclusive carry = inclusive value of segment tseg-1 (same n4l) ----
  float y_re[4] = {0.f, 0.f, 0.f, 0.f};
  float y_im[4] = {0.f, 0.f, 0.f, 0.f};
  if (tseg > 0) {
    const int qc = q - N4PB * 11;
#pragma unroll
    for (int j = 0; j < 4; ++j) { y_re[j] = lds[qc + 2 + j]; y_im[j] = lds[qc + 6 + j]; }
  }

  // ---- pass 2: apply carry (X remat from L2/LLC), store coalesced ----
  const int ob = (b * LL + t0) * (2 * AN) + n4 * 2;  // f32x4 index into out
#pragma unroll
  for (int t = 0; t < TT; ++t) {
    const float are = ar[t], aim = ai[t];
#pragma unroll
    for (int j = 0; j < 4; ++j) {
      const float ny_re = are * y_re[j] - aim * y_im[j] + xr[t][j];
      const float ny_im = are * y_im[j] + aim * y_re[j] + xi[t][j];
      y_re[j] = ny_re; y_im[j] = ny_im;
    }
    f32x4 o0 = {y_re[0], y_im[0], y_re[1], y_im[1]};
    f32x4 o1 = {y_re[2], y_im[2], y_re[3], y_im[3]};
    out4[ob + t * (2 * AN)]     = o0;
    out4[ob + t * (2 * AN) + 1] = o1;
  }
}

extern "C" void kernel_launch(void* const* d_in, const int* in_sizes, int n_in,
                              void* d_out, int out_size, void* d_ws, size_t ws_size,
                              hipStream_t stream) {
  const float* A_re  = (const float*)d_in[0];
  const float* A_im  = (const float*)d_in[1];
  const f32x4* X_re4 = (const f32x4*)d_in[2];
  const f32x4* X_im4 = (const f32x4*)d_in[3];
  f32x4* out4 = (f32x4*)d_out;
  (void)d_ws; (void)ws_size;  // no workspace needed

  const int blocks = BB * (AN / N4PB);   // 256 blocks: one per (b, 4-n4 group)
  pscan_onepass3<<<blocks, TPB, 0, stream>>>(A_re, A_im, X_re4, X_im4, out4);
}